// Round 12
// baseline (585.587 us; speedup 1.0000x reference)
//
#include <hip/hip_runtime.h>
#include <hip/hip_bf16.h>

// Sparse MoE: T=2048, D=1024, E=8 routed (H=768, top-2) + shared GatedMLP (1536 hidden)
// decomposed into 2 pseudo-experts of routed shape -> 10 uniform experts.
// R12: TWO nodes. Node1 convgate (full occupancy streaming: conversions + dense top-2
// gate, zero out, zero ctl). Node2 k_fc: 448-block ticket kernel (co-residency proven
// in R11) fusing compaction + fc1 + fc2 with fine-grained producer-consumer counters
// (no full grid barrier; fc2 tiles wait only on their feeder fc1 tiles).

typedef short bf16x8 __attribute__((ext_vector_type(8)));
typedef float f32x4 __attribute__((ext_vector_type(4)));

#define NBLK 448
// ctl layout (ints): [0]=ticket  [16]=ccnt  [32+mt]=fcnt_sh (16)  [64+e*16+mtl]=fcnt_r (128)
#define CTL_TICKET 0
#define CTL_CCNT   16
#define CTL_FSH    32
#define CTL_FR     64

__device__ __forceinline__ unsigned short f2b(float f) {
    __hip_bfloat16 h = __float2bfloat16(f);
    return *reinterpret_cast<unsigned short*>(&h);
}

__device__ __forceinline__ void ldst16(const unsigned short* g, unsigned short* l) {
    __builtin_amdgcn_global_load_lds(
        (const __attribute__((address_space(1))) unsigned int*)g,
        (__attribute__((address_space(3))) unsigned int*)l, 16, 0, 0);
}

__device__ __forceinline__ void cvt8(const float* s, unsigned short* d, int j) {
    const float4* sp = reinterpret_cast<const float4*>(s) + (size_t)j * 2;
    float4 v0 = sp[0], v1 = sp[1];
    union { unsigned short u[8]; uint4 v; } o;
    o.u[0]=f2b(v0.x); o.u[1]=f2b(v0.y); o.u[2]=f2b(v0.z); o.u[3]=f2b(v0.w);
    o.u[4]=f2b(v1.x); o.u[5]=f2b(v1.y); o.u[6]=f2b(v1.z); o.u[7]=f2b(v1.w);
    *(reinterpret_cast<uint4*>(d) + j) = o.v;
}

// ---- Node 1: conversions (blocks 0..2879) + dense gate (2880..4927) + zero ctl ------
__global__ __launch_bounds__(256) void k_convgate(const float* __restrict__ x,
                                                  const float* __restrict__ gw,
                                                  const float* __restrict__ W1,
                                                  const float* __restrict__ Ws1,
                                                  const float* __restrict__ W2,
                                                  const float* __restrict__ Ws2,
                                                  unsigned short* __restrict__ xb,
                                                  unsigned short* __restrict__ W1b,
                                                  unsigned short* __restrict__ Ws1b,
                                                  unsigned short* __restrict__ W2b,
                                                  unsigned short* __restrict__ Ws2b,
                                                  int* __restrict__ topk_e,
                                                  float* __restrict__ topk_w,
                                                  int* __restrict__ ctl,
                                                  float* __restrict__ out) {
    __shared__ float red[4][8];
    __shared__ float sc[8];
    const int b = blockIdx.x, tid = threadIdx.x;
    if (b < 2880) {
        if (b == 0 && tid < 192) ctl[tid] = 0;
        for (int q = 0; q < 4; q++) {
            int i = b * 1024 + q * 256 + tid;       // 2880*1024 == 2949120 exactly
            if (i < 1572864)       cvt8(W1,  W1b,  i);
            else if (i < 1966080)  cvt8(Ws1, Ws1b, i - 1572864);
            else if (i < 2752512)  cvt8(W2,  W2b,  i - 1966080);
            else                   cvt8(Ws2, Ws2b, i - 2752512);
        }
        return;
    }
    const int t = b - 2880;
    const int lane = tid & 63, w = tid >> 6;

    float4 v = reinterpret_cast<const float4*>(x + (size_t)t * 1024)[tid];
    union { unsigned short u[4]; } o;
    o.u[0]=f2b(v.x); o.u[1]=f2b(v.y); o.u[2]=f2b(v.z); o.u[3]=f2b(v.w);
    reinterpret_cast<ushort4*>(xb + (size_t)t * 1024)[tid] = *(ushort4*)o.u;

    float p[8];
    for (int e = 0; e < 8; e++) {
        float4 g = reinterpret_cast<const float4*>(gw + (size_t)e * 1024)[tid];
        p[e] = v.x*g.x + v.y*g.y + v.z*g.z + v.w*g.w;
    }
    for (int e = 0; e < 8; e++)
        for (int off = 32; off > 0; off >>= 1) p[e] += __shfl_down(p[e], off, 64);
    if (lane == 0)
        for (int e = 0; e < 8; e++) red[w][e] = p[e];
    __syncthreads();
    if (tid < 8) sc[tid] = red[0][tid] + red[1][tid] + red[2][tid] + red[3][tid];
    __syncthreads();
    if (tid == 0) {
        float m = sc[0];
        for (int e = 1; e < 8; e++) m = fmaxf(m, sc[e]);
        float ex[8], sum = 0.f;
        for (int e = 0; e < 8; e++) { ex[e] = expf(sc[e] - m); sum += ex[e]; }
        float inv = 1.f / sum;
        int i1 = 0;
        for (int e = 1; e < 8; e++) if (sc[e] > sc[i1]) i1 = e;
        int i2 = -1; float s2 = -1e30f;
        for (int e = 0; e < 8; e++) if (e != i1 && sc[e] > s2) { s2 = sc[e]; i2 = e; }
        topk_e[t * 2]     = i1; topk_w[t * 2]     = ex[i1] * inv;
        topk_e[t * 2 + 1] = i2; topk_w[t * 2 + 1] = ex[i2] * inv;
    }
    reinterpret_cast<float4*>(out + (size_t)t * 1024)[tid] = (float4){0.f, 0.f, 0.f, 0.f};
}

// ---- Node 2: ticket kernel: compaction(8) -> fc1 pseudo(384) -> fc1 routed(480)
//      -> fc2 shared(256) -> fc2 routed(640). 448 blocks, all co-resident.
__global__ __launch_bounds__(256, 2) void k_fc(const unsigned short* __restrict__ xb,
                                               const unsigned short* __restrict__ W1b,
                                               const unsigned short* __restrict__ Ws1b,
                                               const unsigned short* __restrict__ W2b,
                                               const unsigned short* __restrict__ Ws2b,
                                               const int* __restrict__ topk_e,
                                               const float* __restrict__ topk_w,
                                               int* __restrict__ tokslot,
                                               float* __restrict__ wroute,
                                               int* __restrict__ cnt,
                                               int* __restrict__ ctl,
                                               unsigned short* __restrict__ act_r,
                                               unsigned short* __restrict__ acts,
                                               float* __restrict__ out) {
    __shared__ alignas(16) unsigned short smem[16384];   // 32KB
    __shared__ int sTile, sLc;
    const int tid = threadIdx.x;
    const int lane = tid & 63, w = tid >> 6;
    const int wr = w >> 1, wc = w & 1;
    const int lm = lane & 15, cqb = lane >> 4;
    unsigned short* As = smem;
    unsigned short* Bs = smem + 8192;

    for (;;) {
        __syncthreads();
        if (tid == 0) sTile = atomicAdd(&ctl[CTL_TICKET], 1);
        __syncthreads();
        const int tk = sTile;
        if (tk >= 1768) break;

        if (tk < 8) {
            // ---- compaction for expert tk ----
            const int e = tk;
            if (tid == 0) sLc = 0;
            __syncthreads();
            for (int q = 0; q < 8; q++) {
                int t = q * 256 + tid;
                int hit = -1;
                if (topk_e[t * 2] == e) hit = 0;
                else if (topk_e[t * 2 + 1] == e) hit = 1;
                if (hit >= 0) {
                    int pos = atomicAdd(&sLc, 1);
                    tokslot[e * 2048 + pos] = t;
                    wroute[e * 2048 + pos]  = topk_w[t * 2 + hit];
                }
            }
            __syncthreads();
            if (tid == 0) cnt[e * 16] = sLc;
            __threadfence();
            __syncthreads();
            if (tid == 0) atomicAdd(&ctl[CTL_CCNT], 1);
            continue;
        }

        if (tk < 872) {
            // ---- fc1 tile (M128 x N64 (y+g), BK=64, K=1024) ----
            int e, m0, ht, mtl = 0;
            if (tk < 392) {               // pseudo experts, no wait
                int idx = tk - 8;
                e = 8 + idx / 192; int rem = idx % 192;
                mtl = rem / 12; ht = rem % 12; m0 = mtl * 128;
            } else {                      // routed: wait for all compactions
                if (tid == 0)
                    while (__hip_atomic_load(&ctl[CTL_CCNT], __ATOMIC_ACQUIRE,
                                             __HIP_MEMORY_SCOPE_AGENT) < 8)
                        __builtin_amdgcn_s_sleep(1);
                __syncthreads();
                __threadfence();
                int idx = tk - 392;
                int mtr = idx / 12; ht = idx % 12;
                int pre = 0, sel = -1, base = 0;
                for (int ee = 0; ee < 8; ee++) {
                    int til = (cnt[ee * 16] + 127) >> 7;
                    if (sel < 0 && mtr < pre + til) { sel = ee; base = pre; }
                    pre += til;
                }
                if (sel < 0) continue;
                e = sel; mtl = mtr - base; m0 = mtl * 128;
            }
            const int h0 = ht * 64;
            const int Te = (e < 8) ? cnt[e * 16] : 2048;
            const unsigned short* Bp = (e < 8) ? (W1b + (size_t)e * 1536 * 1024)
                                               : (Ws1b + (size_t)(e - 8) * 768 * 1024);
            const int gOff = (e < 8) ? 768 : 1536;

            const int kc = tid & 7;
            int aoff[4], boff[4];
            for (int q = 0; q < 4; q++) {
                int row = q * 32 + (tid >> 3);
                int ko = ((kc ^ (row & 7)) << 3);
                int idx2 = m0 + row;
                int tkn = (e < 8) ? ((idx2 < Te) ? tokslot[e * 2048 + idx2] : 0) : idx2;
                aoff[q] = tkn * 1024 + ko;
                int grow = (row < 64) ? (h0 + row) : (gOff + h0 + row - 64);
                boff[q] = grow * 1024 + ko;
            }

            f32x4 accy[4][2], accg[4][2];
            for (int i = 0; i < 4; i++)
                for (int j = 0; j < 2; j++) {
                    accy[i][j] = (f32x4){0.f, 0.f, 0.f, 0.f};
                    accg[i][j] = (f32x4){0.f, 0.f, 0.f, 0.f};
                }

            for (int k0 = 0; k0 < 1024; k0 += 64) {
                for (int q = 0; q < 4; q++) {
                    ldst16(xb + aoff[q] + k0, As + (q * 256 + tid) * 8);
                    ldst16(Bp + boff[q] + k0, Bs + (q * 256 + tid) * 8);
                }
                __syncthreads();
                for (int kh = 0; kh < 2; kh++) {
                    const int cq = kh * 4 + cqb;
                    bf16x8 a[4], by[2], bg[2];
                    for (int i = 0; i < 4; i++) {
                        int r = 64 * wr + 16 * i + lm;
                        a[i] = *(const bf16x8*)&As[r * 64 + ((cq ^ (r & 7)) << 3)];
                    }
                    for (int j = 0; j < 2; j++) {
                        int ry = 32 * wc + 16 * j + lm;
                        by[j] = *(const bf16x8*)&Bs[ry * 64 + ((cq ^ (ry & 7)) << 3)];
                        int rg = 64 + ry;
                        bg[j] = *(const bf16x8*)&Bs[rg * 64 + ((cq ^ (rg & 7)) << 3)];
                    }
                    for (int i = 0; i < 4; i++)
                        for (int j = 0; j < 2; j++) {
                            accy[i][j] = __builtin_amdgcn_mfma_f32_16x16x32_bf16(a[i], by[j], accy[i][j], 0, 0, 0);
                            accg[i][j] = __builtin_amdgcn_mfma_f32_16x16x32_bf16(a[i], bg[j], accg[i][j], 0, 0, 0);
                        }
                }
                __syncthreads();
            }

            for (int i = 0; i < 4; i++)
                for (int r2 = 0; r2 < 4; r2++) {
                    int irow = m0 + 64 * wr + 16 * i + ((lane >> 4) << 2) + r2;
                    if (irow >= Te) continue;
                    float sw = (e < 8) ? wroute[e * 2048 + irow] : 1.0f;
                    unsigned short* dst = (e < 8)
                        ? (act_r + ((size_t)e * 2048 + irow) * 768)
                        : (acts + (size_t)irow * 1536 + (size_t)(e - 8) * 768);
                    for (int j = 0; j < 2; j++) {
                        float y = accy[i][j][r2], g = accg[i][j][r2];
                        float sg = g / (1.0f + __expf(-g));
                        dst[h0 + 32 * wc + 16 * j + lm] = f2b(sw * y * sg);
                    }
                }
            __threadfence();
            __syncthreads();
            if (tid == 0) {
                if (e < 8) atomicAdd(&ctl[CTL_FR + e * 16 + mtl], 1);
                else       atomicAdd(&ctl[CTL_FSH + (m0 >> 7)], 1);
            }
            continue;
        }

        // ---- fc2 tile (M128 x N64, BK=64) ----
        int e, m0, n0, K, stride, Te;
        const unsigned short *Ab, *Bb;
        if (tk < 1128) {                  // shared: wait fcnt_sh[mt]==24
            int idx = tk - 872;
            int mt = idx / 16; n0 = (idx % 16) * 64;
            if (tid == 0)
                while (__hip_atomic_load(&ctl[CTL_FSH + mt], __ATOMIC_ACQUIRE,
                                         __HIP_MEMORY_SCOPE_AGENT) < 24)
                    __builtin_amdgcn_s_sleep(1);
            __syncthreads();
            __threadfence();
            e = 8; m0 = mt * 128; K = 1536; stride = 1536; Te = 2048;
            Ab = acts; Bb = Ws2b;
        } else {                          // routed: wait compaction, map, wait feeders
            if (tid == 0)
                while (__hip_atomic_load(&ctl[CTL_CCNT], __ATOMIC_ACQUIRE,
                                         __HIP_MEMORY_SCOPE_AGENT) < 8)
                    __builtin_amdgcn_s_sleep(1);
            __syncthreads();
            __threadfence();
            int idx = tk - 1128;
            int mtr = idx / 16; n0 = (idx % 16) * 64;
            int pre = 0, sel = -1, base = 0;
            for (int ee = 0; ee < 8; ee++) {
                int til = (cnt[ee * 16] + 127) >> 7;
                if (sel < 0 && mtr < pre + til) { sel = ee; base = pre; }
                pre += til;
            }
            if (sel < 0) continue;
            e = sel; int mtl = mtr - base; m0 = mtl * 128;
            if (tid == 0)
                while (__hip_atomic_load(&ctl[CTL_FR + e * 16 + mtl], __ATOMIC_ACQUIRE,
                                         __HIP_MEMORY_SCOPE_AGENT) < 12)
                    __builtin_amdgcn_s_sleep(1);
            __syncthreads();
            __threadfence();
            K = 768; stride = 768; Te = cnt[e * 16];
            Ab = act_r + (size_t)e * 2048 * 768;
            Bb = W2b + (size_t)e * 1024 * 768;
        }

        int aoff[4], boff[2];
        for (int q = 0; q < 4; q++) {
            int ch = q * 256 + tid;
            int row = ch >> 3, c = ch & 7;
            aoff[q] = (m0 + row) * stride + ((c ^ (row & 7)) << 3);
        }
        for (int q = 0; q < 2; q++) {
            int ch = q * 256 + tid;
            int row = ch >> 3, c = ch & 7;
            boff[q] = (n0 + row) * stride + ((c ^ (row & 7)) << 3);
        }

        f32x4 acc[4][2];
        for (int i = 0; i < 4; i++)
            for (int j = 0; j < 2; j++) acc[i][j] = (f32x4){0.f, 0.f, 0.f, 0.f};

        for (int k0 = 0; k0 < K; k0 += 64) {
            for (int q = 0; q < 4; q++) ldst16(Ab + aoff[q] + k0, As + (q * 256 + tid) * 8);
            for (int q = 0; q < 2; q++) ldst16(Bb + boff[q] + k0, Bs + (q * 256 + tid) * 8);
            __syncthreads();
            for (int kh = 0; kh < 2; kh++) {
                const int cq = kh * 4 + cqb;
                bf16x8 a[4], bb[2];
                for (int i = 0; i < 4; i++) {
                    int r = 64 * wr + 16 * i + lm;
                    a[i] = *(const bf16x8*)&As[r * 64 + ((cq ^ (r & 7)) << 3)];
                }
                for (int j = 0; j < 2; j++) {
                    int rb = 32 * wc + 16 * j + lm;
                    bb[j] = *(const bf16x8*)&Bs[rb * 64 + ((cq ^ (rb & 7)) << 3)];
                }
                for (int i = 0; i < 4; i++)
                    for (int j = 0; j < 2; j++)
                        acc[i][j] = __builtin_amdgcn_mfma_f32_16x16x32_bf16(a[i], bb[j], acc[i][j], 0, 0, 0);
            }
            __syncthreads();
        }

        for (int i = 0; i < 4; i++)
            for (int r2 = 0; r2 < 4; r2++) {
                int irow = m0 + 64 * wr + 16 * i + ((lane >> 4) << 2) + r2;
                if (irow >= Te) continue;
                int t = (e < 8) ? tokslot[e * 2048 + irow] : irow;
                for (int j = 0; j < 2; j++) {
                    int col = n0 + 32 * wc + 16 * j + lm;
                    atomicAdd(out + (size_t)t * 1024 + col, acc[i][j][r2]);
                }
            }
    }
}

extern "C" void kernel_launch(void* const* d_in, const int* in_sizes, int n_in,
                              void* d_out, int out_size, void* d_ws, size_t ws_size,
                              hipStream_t stream) {
    const float* x   = (const float*)d_in[0];
    const float* gw  = (const float*)d_in[1];
    const float* W1  = (const float*)d_in[2];
    const float* W2  = (const float*)d_in[3];
    const float* Ws1 = (const float*)d_in[4];
    const float* Ws2 = (const float*)d_in[5];
    float* out = (float*)d_out;

    char* ws = (char*)d_ws;
    unsigned short* xb    = (unsigned short*)(ws + 0);          //  4,194,304
    unsigned short* W1b   = (unsigned short*)(ws + 4194304);    // 25,165,824
    unsigned short* Ws1b  = (unsigned short*)(ws + 29360128);   //  6,291,456
    unsigned short* W2b   = (unsigned short*)(ws + 35651584);   // 12,582,912
    unsigned short* Ws2b  = (unsigned short*)(ws + 48234496);   //  3,145,728
    unsigned short* act_r = (unsigned short*)(ws + 51380224);   // 25,165,824 (8x2048x768)
    unsigned short* acts  = (unsigned short*)(ws + 76546048);   //  6,291,456 (2048x1536)
    int*            tokslot = (int*)(ws + 82837504);            //     65,536 (8x2048)
    float*          wroute  = (float*)(ws + 82903040);          //     65,536
    int*            cnt     = (int*)(ws + 82968576);            //        512 (8x16 ints)
    int*            topk_e  = (int*)(ws + 82969088);            //     16,384
    float*          topk_w  = (float*)(ws + 82985472);          //     16,384
    int*            ctl     = (int*)(ws + 83001856);            //        768 (192 ints)

    k_convgate<<<4928, 256, 0, stream>>>(x, gw, W1, Ws1, W2, Ws2,
                                         xb, W1b, Ws1b, W2b, Ws2b,
                                         topk_e, topk_w, ctl, out);
    k_fc<<<NBLK, 256, 0, stream>>>(xb, W1b, Ws1b, W2b, Ws2b, topk_e, topk_w,
                                   tokslot, wroute, cnt, ctl, act_r, acts, out);
}